// Round 3
// baseline (416.163 us; speedup 1.0000x reference)
//
#include <hip/hip_runtime.h>

#define HH 384
#define HWPX (HH*HH)

// ws float-offset layout
#define WOFF3 16
#define HS3   40      // D=3,  DP=4 : 2*3*4  + 3*4  + 4
#define WOFF6 256     // 16 + 6*40
#define HS6   328     // D=12, DP=12: 2*12*12+ 3*12 + 4
#define WOFF9 1568    // 256 + 4*328
#define HS9   1600    // D=27, DP=28: 2*27*28+ 3*28 + 4
#define CATOFF 8192
#define P9BOFF (CATOFF + 2*9*HWPX)            // 2662400 floats
#define WS_NEED ((size_t)(P9BOFF + 2*3*HWPX) * 4)   // ~14.2 MB

// ---------------- precompute weights + xg max ----------------
__global__ __launch_bounds__(256) void pre_xg(
    const float* __restrict__ w3q, const float* __restrict__ b3q,
    const float* __restrict__ w3k, const float* __restrict__ b3k,
    const float* __restrict__ w3v, const float* __restrict__ b3v, const float* __restrict__ hw3,
    const float* __restrict__ w6q, const float* __restrict__ b6q,
    const float* __restrict__ w6k, const float* __restrict__ b6k,
    const float* __restrict__ w6v, const float* __restrict__ b6v, const float* __restrict__ hw6,
    const float* __restrict__ w9q, const float* __restrict__ b9q,
    const float* __restrict__ w9k, const float* __restrict__ b9k,
    const float* __restrict__ w9v, const float* __restrict__ b9v, const float* __restrict__ hw9,
    const float* __restrict__ x, float* __restrict__ ws)
{
    __shared__ float sm[4];
    const int blk = blockIdx.x;
    const int tid = threadIdx.x;

    if (blk < 12) {
        int stage = blk < 6 ? 0 : (blk < 10 ? 1 : 2);
        int h = blk - (stage == 0 ? 0 : (stage == 1 ? 6 : 10));
        const float* WQ[3] = {w3q, w6q, w9q};
        const float* BQ[3] = {b3q, b6q, b9q};
        const float* WK[3] = {w3k, w6k, w9k};
        const float* BK[3] = {b3k, b6k, b9k};
        const float* WV_[3] = {w3v, w6v, w9v};
        const float* BV[3] = {b3v, b6v, b9v};
        const float* HWp[3] = {hw3, hw6, hw9};
        const int Ds[3] = {3, 12, 27};
        const int DPs[3] = {4, 12, 28};
        const int WOFFs[3] = {WOFF3, WOFF6, WOFF9};
        const int HSs[3] = {HS3, HS6, HS9};

        const int D = Ds[stage], DP = DPs[stage];
        const float* wq = WQ[stage] + h * D * D;
        const float* bq = BQ[stage] + h * D;
        const float* wk = WK[stage] + h * D * D;
        const float* bk = BK[stage] + h * D;
        const float* wv = WV_[stage] + h * D * D;
        const float* bv = BV[stage] + h * D;
        const float hwv = HWp[stage][h];
        float* base = ws + WOFFs[stage] + h * HSs[stage];
        const float scale = rsqrtf((float)D);

        for (int i = tid; i < D * DP; i += 256) {
            int a = i / DP, b = i % DP;
            float m = 0.f;
            if (b < D) for (int e = 0; e < D; ++e) m += wk[e * D + b] * wq[e * D + a];
            base[i] = scale * m;                       // M[a][d]
            float wvv = 0.f;
            if (b < D) wvv = hwv * wv[a * D + b];
            base[D * DP + i] = wvv;                    // WV[e][d]
        }
        for (int i = tid; i < DP; i += 256) {
            float cv = 0.f, uv = 0.f;
            if (i < D) for (int e = 0; e < D; ++e) {
                cv += bq[e] * wk[e * D + i];
                uv += wq[e * D + i] * bk[e];
            }
            base[2 * D * DP + i] = scale * cv;         // c
            base[2 * D * DP + DP + i] = scale * uv;    // u
            base[2 * D * DP + 2 * DP + i] = (i < D) ? hwv * bv[i] : 0.f;   // bvh
        }
        if (tid == 0) {
            float s = 0.f;
            for (int e = 0; e < D; ++e) s += bq[e] * bk[e];
            base[2 * D * DP + 3 * DP] = scale * s;     // s0
        }
    } else {
        // xg: 288 chunk-blocks, b = chunk/144
        int i2 = blk - 12;
        int b = i2 / 144, chunk = i2 % 144;
        const float4* xb = (const float4*)(x + (size_t)b * 3 * HWPX + chunk * 3072);
        float m = 0.f;
        for (int j = tid; j < 768; j += 256) {
            float4 v = xb[j];
            m = fmaxf(m, fmaxf(fmaxf(v.x, v.y), fmaxf(v.z, v.w)));
        }
        for (int off = 32; off; off >>= 1)
            m = fmaxf(m, __shfl_down(m, off));
        if ((tid & 63) == 0) sm[tid >> 6] = m;
        __syncthreads();
        if (tid == 0) {
            float mm = fmaxf(fmaxf(sm[0], sm[1]), fmaxf(sm[2], sm[3]));
            atomicMax((int*)&ws[b], __float_as_int(mm));  // poison 0xAA.. is negative int; mm>=0 wins
        }
    }
}

// ---------------- attention, neighborhood-in-registers (P<=2) ----------------
template <int P, int HEADS, int TW, int TH>
__global__ __launch_bounds__(TW * TH) void attn_reg(
    const float* __restrict__ in, int in_bstride,
    float* __restrict__ out, int out_bstride,
    const float* __restrict__ wsw)
{
    constexpr int C = 3, D = C * P * P, DP = (D + 3) & ~3, HS = 2 * D * DP + 3 * DP + 4;
    constexpr int TILE_H = (TH + 2) * P, TILE_W = (TW + 2) * P;
    constexpr int TILE_WP = ((TILE_W + 2) % 32 == 0) ? TILE_W + 4 : TILE_W + 2;
    constexpr int NT = TW * TH;
    __shared__ float tile[C][TILE_H][TILE_WP];

    const int tid = threadIdx.x;
    const int b = blockIdx.z;
    const int by = blockIdx.y * TH, bx = blockIdx.x * TW;
    const int base_y = by * P - P, base_x = bx * P - P;
    const float* inb = in + (size_t)b * in_bstride;

    for (int i = tid; i < C * TILE_H * TILE_WP; i += NT) {
        int c = i / (TILE_H * TILE_WP);
        int rem = i % (TILE_H * TILE_WP);
        int ty = rem / TILE_WP, tx = rem % TILE_WP;
        int y = base_y + ty; y = y < 0 ? -y : (y >= HH ? 2 * HH - 2 - y : y);
        int x = base_x + tx; x = x < 0 ? -x : (x >= HH ? 2 * HH - 2 - x : x);
        (&tile[0][0][0])[i] = inb[c * HWPX + y * HH + x];
    }
    __syncthreads();

    const int wx = tid % TW, wy = tid / TW;

    float T[9][D];
#pragma unroll
    for (int di = 0; di < 3; ++di)
#pragma unroll
        for (int dj = 0; dj < 3; ++dj)
#pragma unroll
            for (int c = 0; c < C; ++c)
#pragma unroll
                for (int r = 0; r < P; ++r)
#pragma unroll
                    for (int s = 0; s < P; ++s)
                        T[di * 3 + dj][(c * P + r) * P + s] =
                            tile[c][(wy + di) * P + r][(wx + dj) * P + s];

    float mixed[D];
#pragma unroll
    for (int e = 0; e < D; ++e) mixed[e] = 0.f;

#pragma unroll 1
    for (int h = 0; h < HEADS; ++h) {
        const float* __restrict__ Mb = wsw + h * HS;
        const float* __restrict__ cc = Mb + 2 * D * DP;
        float qk[D];
        float su = cc[3 * DP];
#pragma unroll
        for (int d = 0; d < D; ++d) qk[d] = cc[d];
#pragma unroll
        for (int a = 0; a < D; ++a) {
            const float t = T[4][a];
            su += cc[DP + a] * t;
#pragma unroll
            for (int d = 0; d < D; ++d) qk[d] += Mb[a * DP + d] * t;
        }
        float sc[9];
#pragma unroll
        for (int p = 0; p < 9; ++p) {
            float s = su;
#pragma unroll
            for (int d = 0; d < D; ++d) s += qk[d] * T[p][d];
            sc[p] = s;
        }
        float m = sc[0];
#pragma unroll
        for (int p = 1; p < 9; ++p) m = fmaxf(m, sc[p]);
        float sum = 0.f;
#pragma unroll
        for (int p = 0; p < 9; ++p) { sc[p] = __expf(sc[p] - m); sum += sc[p]; }
        const float inv = 1.f / sum;
        float wt[D];
#pragma unroll
        for (int d = 0; d < D; ++d) wt[d] = 0.f;
#pragma unroll
        for (int p = 0; p < 9; ++p) {
            const float a = sc[p] * inv;
#pragma unroll
            for (int d = 0; d < D; ++d) wt[d] += a * T[p][d];
        }
#pragma unroll
        for (int e = 0; e < D; ++e) {
            float o = cc[2 * DP + e];
#pragma unroll
            for (int d = 0; d < D; ++d) o += Mb[D * DP + e * DP + d] * wt[d];
            mixed[e] += o;
        }
    }

    float* outb = out + (size_t)b * out_bstride;
#pragma unroll
    for (int c = 0; c < C; ++c)
#pragma unroll
        for (int r = 0; r < P; ++r)
#pragma unroll
            for (int s = 0; s < P; ++s)
                outb[c * HWPX + ((by + wy) * P + r) * HH + (bx + wx) * P + s] =
                    mixed[(c * P + r) * P + s];
}

// ---------------- stage9 (P=3), two-pass tile, head split across blockIdx.z ----------------
template <int HSPLIT, int TW, int TH>
__global__ __launch_bounds__(TW * TH) void attn9k(
    const float* __restrict__ in,      // cat + 3*HWPX, bstride 9*HWPX
    float* __restrict__ catOut,        // cat base (ch0..2), bstride 9*HWPX
    float* __restrict__ p9b,           // [2][3][HWPX]
    const float* __restrict__ wsw)
{
    constexpr int P = 3, C = 3, D = 27, DP = 28, HS = HS9;
    constexpr int HPT = 2 / HSPLIT;
    constexpr int TILE_H = (TH + 2) * P, TILE_W = (TW + 2) * P;
    constexpr int TILE_WP = ((TILE_W + 2) % 32 == 0) ? TILE_W + 4 : TILE_W + 2;
    constexpr int NT = TW * TH;
    __shared__ float tile[C][TILE_H][TILE_WP];

    const int tid = threadIdx.x;
    const int z = blockIdx.z;
    const int b = z & 1;
    const int hs = (HSPLIT == 2) ? (z >> 1) : 0;
    const int by = blockIdx.y * TH, bx = blockIdx.x * TW;
    const int base_y = by * P - P, base_x = bx * P - P;
    const float* inb = in + (size_t)b * 9 * HWPX;

    for (int i = tid; i < C * TILE_H * TILE_WP; i += NT) {
        int c = i / (TILE_H * TILE_WP);
        int rem = i % (TILE_H * TILE_WP);
        int ty = rem / TILE_WP, tx = rem % TILE_WP;
        int y = base_y + ty; y = y < 0 ? -y : (y >= HH ? 2 * HH - 2 - y : y);
        int x = base_x + tx; x = x < 0 ? -x : (x >= HH ? 2 * HH - 2 - x : x);
        (&tile[0][0][0])[i] = inb[c * HWPX + y * HH + x];
    }
    __syncthreads();

    const int wx = tid % TW, wy = tid / TW;

    float mixed[D];
#pragma unroll
    for (int e = 0; e < D; ++e) mixed[e] = 0.f;

#pragma unroll 1
    for (int h = hs * HPT; h < hs * HPT + HPT; ++h) {
        const float* __restrict__ Mb = wsw + h * HS;
        const float* __restrict__ cc = Mb + 2 * D * DP;
        float qk[D];
        float su = cc[3 * DP];
#pragma unroll
        for (int d = 0; d < D; ++d) qk[d] = cc[d];
#pragma unroll
        for (int c = 0; c < C; ++c)
#pragma unroll
            for (int r = 0; r < P; ++r)
#pragma unroll
                for (int s = 0; s < P; ++s) {
                    const int a = (c * P + r) * P + s;
                    const float t = tile[c][(wy + 1) * P + r][(wx + 1) * P + s];
                    su += cc[DP + a] * t;
#pragma unroll
                    for (int d = 0; d < D; ++d) qk[d] += Mb[a * DP + d] * t;
                }
        float sc[9];
#pragma unroll
        for (int di = 0; di < 3; ++di)
#pragma unroll
            for (int dj = 0; dj < 3; ++dj) {
                float s = su;
#pragma unroll
                for (int c = 0; c < C; ++c)
#pragma unroll
                    for (int r = 0; r < P; ++r)
#pragma unroll
                        for (int ss = 0; ss < P; ++ss)
                            s += qk[(c * P + r) * P + ss] *
                                 tile[c][(wy + di) * P + r][(wx + dj) * P + ss];
                sc[di * 3 + dj] = s;
            }
        float m = sc[0];
#pragma unroll
        for (int p = 1; p < 9; ++p) m = fmaxf(m, sc[p]);
        float sum = 0.f;
#pragma unroll
        for (int p = 0; p < 9; ++p) { sc[p] = __expf(sc[p] - m); sum += sc[p]; }
        const float inv = 1.f / sum;
        float wt[D];
#pragma unroll
        for (int d = 0; d < D; ++d) wt[d] = 0.f;
#pragma unroll
        for (int di = 0; di < 3; ++di)
#pragma unroll
            for (int dj = 0; dj < 3; ++dj) {
                const float a = sc[di * 3 + dj] * inv;
#pragma unroll
                for (int c = 0; c < C; ++c)
#pragma unroll
                    for (int r = 0; r < P; ++r)
#pragma unroll
                        for (int ss = 0; ss < P; ++ss)
                            wt[(c * P + r) * P + ss] += a *
                                tile[c][(wy + di) * P + r][(wx + dj) * P + ss];
            }
#pragma unroll
        for (int e = 0; e < D; ++e) {
            float o = cc[2 * DP + e];
#pragma unroll
            for (int d = 0; d < D; ++d) o += Mb[D * DP + e * DP + d] * wt[d];
            mixed[e] += o;
        }
    }

    float* outb = (HSPLIT == 2 && hs == 1) ? (p9b + (size_t)b * 3 * HWPX)
                                           : (catOut + (size_t)b * 9 * HWPX);
#pragma unroll
    for (int c = 0; c < C; ++c)
#pragma unroll
        for (int r = 0; r < P; ++r)
#pragma unroll
            for (int s = 0; s < P; ++s)
                outb[c * HWPX + ((by + wy) * P + r) * HH + (bx + wx) * P + s] =
                    mixed[(c * P + r) * P + s];
}

// ---------------- conv0 (5x5, zero-pad 2) + final elementwise ----------------
// 32x16 output tile, 128 threads, tile[9][20][40] float4-staged
__global__ __launch_bounds__(128) void conv_final(
    const float* __restrict__ cat, const float* __restrict__ p9b, int addp9,
    const float* __restrict__ w, const float* __restrict__ bias,
    const float* __restrict__ x, const float* __restrict__ xg,
    float* __restrict__ out)
{
    __shared__ float tile[9][20][40];
    const int tid = threadIdx.x;
    const int b = blockIdx.z;
    const int bx = blockIdx.x * 32, by = blockIdx.y * 16;
    const float* catb = cat + (size_t)b * 9 * HWPX;
    const float* p9bb = p9b + (size_t)b * 3 * HWPX;

    for (int i = tid; i < 9 * 20 * 10; i += 128) {
        int ci = i / 200;
        int rem = i % 200;
        int row = rem / 10, c4 = rem % 10;
        int y = by + row - 2, xx = bx - 4 + 4 * c4;
        float4 v = {0.f, 0.f, 0.f, 0.f};
        if (y >= 0 && y < HH && xx >= 0 && xx <= HH - 4) {
            v = *(const float4*)&catb[ci * HWPX + y * HH + xx];
            if (addp9 && ci < 3) {
                float4 u = *(const float4*)&p9bb[ci * HWPX + y * HH + xx];
                v.x += u.x; v.y += u.y; v.z += u.z; v.w += u.w;
            }
        }
        *(float4*)&tile[ci][row][4 * c4] = v;
    }
    __syncthreads();

    const int tx = tid & 7, ty = tid >> 3;     // 8 col-groups x 16 rows
    float acc0[4], acc1[4], acc2[4];
    const float b0 = bias[0], b1 = bias[1], b2 = bias[2];
#pragma unroll
    for (int j = 0; j < 4; ++j) { acc0[j] = b0; acc1[j] = b1; acc2[j] = b2; }

#pragma unroll
    for (int ky = 0; ky < 5; ++ky) {
#pragma unroll 1
        for (int ci = 0; ci < 9; ++ci) {
            const float4 ra = *(const float4*)&tile[ci][ty + ky][4 * tx];
            const float4 rb = *(const float4*)&tile[ci][ty + ky][4 * tx + 4];
            const float4 rc = *(const float4*)&tile[ci][ty + ky][4 * tx + 8];
            const float r[12] = {ra.x, ra.y, ra.z, ra.w, rb.x, rb.y, rb.z, rb.w,
                                 rc.x, rc.y, rc.z, rc.w};
            const float* __restrict__ w0 = w + (0 * 9 + ci) * 25 + ky * 5;
            const float* __restrict__ w1 = w + (1 * 9 + ci) * 25 + ky * 5;
            const float* __restrict__ w2 = w + (2 * 9 + ci) * 25 + ky * 5;
#pragma unroll
            for (int j = 0; j < 4; ++j)
#pragma unroll
                for (int kx = 0; kx < 5; ++kx) {
                    const float t = r[j + kx + 2];
                    acc0[j] += t * w0[kx];
                    acc1[j] += t * w1[kx];
                    acc2[j] += t * w2[kx];
                }
        }
    }

    const int yb = by + ty, xb = bx + 4 * tx;
    const float xgv = xg[b];
    float* accs[3] = {acc0, acc1, acc2};
#pragma unroll
    for (int co = 0; co < 3; ++co) {
        const float4 xv = *(const float4*)&x[((size_t)(b * 3 + co)) * HWPX + yb * HH + xb];
        const float* a = accs[co];
        float4 ov;
        float x0;
        x0 = fmaxf(a[0], 0.f); ov.x = fmaxf(xv.x * x0 + xgv - x0, 0.f);
        x0 = fmaxf(a[1], 0.f); ov.y = fmaxf(xv.y * x0 + xgv - x0, 0.f);
        x0 = fmaxf(a[2], 0.f); ov.z = fmaxf(xv.z * x0 + xgv - x0, 0.f);
        x0 = fmaxf(a[3], 0.f); ov.w = fmaxf(xv.w * x0 + xgv - x0, 0.f);
        *(float4*)&out[((size_t)(b * 3 + co)) * HWPX + yb * HH + xb] = ov;
    }
}

// ---------------- launch ----------------
extern "C" void kernel_launch(void* const* d_in, const int* in_sizes, int n_in,
                              void* d_out, int out_size, void* d_ws, size_t ws_size,
                              hipStream_t stream) {
    const float* x   = (const float*)d_in[0];
    const float* w3q = (const float*)d_in[1];
    const float* b3q = (const float*)d_in[2];
    const float* w3k = (const float*)d_in[3];
    const float* b3k = (const float*)d_in[4];
    const float* w3v = (const float*)d_in[5];
    const float* b3v = (const float*)d_in[6];
    const float* hw3 = (const float*)d_in[7];
    const float* w6q = (const float*)d_in[8];
    const float* b6q = (const float*)d_in[9];
    const float* w6k = (const float*)d_in[10];
    const float* b6k = (const float*)d_in[11];
    const float* w6v = (const float*)d_in[12];
    const float* b6v = (const float*)d_in[13];
    const float* hw6 = (const float*)d_in[14];
    const float* w9q = (const float*)d_in[15];
    const float* b9q = (const float*)d_in[16];
    const float* w9k = (const float*)d_in[17];
    const float* b9k = (const float*)d_in[18];
    const float* w9v = (const float*)d_in[19];
    const float* b9v = (const float*)d_in[20];
    const float* hw9 = (const float*)d_in[21];
    const float* c0w = (const float*)d_in[22];
    const float* c0b = (const float*)d_in[23];

    float* out = (float*)d_out;
    float* ws  = (float*)d_ws;
    float* cat = ws + CATOFF;
    float* p9b = ws + P9BOFF;
    const bool split9 = ws_size >= WS_NEED;

    pre_xg<<<300, 256, 0, stream>>>(
        w3q, b3q, w3k, b3k, w3v, b3v, hw3,
        w6q, b6q, w6k, b6k, w6v, b6v, hw6,
        w9q, b9q, w9k, b9k, w9v, b9v, hw9, x, ws);

    // stage3: p=1, 6 heads -> cat ch6..8
    attn_reg<1, 6, 16, 16><<<dim3(24, 24, 2), 256, 0, stream>>>(
        x, 3 * HWPX, cat + 6 * HWPX, 9 * HWPX, ws + WOFF3);
    // stage6: p=2, 4 heads -> cat ch3..5
    attn_reg<2, 4, 8, 8><<<dim3(24, 24, 2), 64, 0, stream>>>(
        cat + 6 * HWPX, 9 * HWPX, cat + 3 * HWPX, 9 * HWPX, ws + WOFF6);
    // stage9: p=3, 2 heads
    if (split9)
        attn9k<2, 8, 8><<<dim3(16, 16, 4), 64, 0, stream>>>(
            cat + 3 * HWPX, cat, p9b, ws + WOFF9);
    else
        attn9k<1, 8, 8><<<dim3(16, 16, 2), 64, 0, stream>>>(
            cat + 3 * HWPX, cat, p9b, ws + WOFF9);

    conv_final<<<dim3(12, 24, 2), 128, 0, stream>>>(
        cat, p9b, split9 ? 1 : 0, c0w, c0b, x, ws, out);
}

// Round 4
// 216.493 us; speedup vs baseline: 1.9223x; 1.9223x over previous
//
#include <hip/hip_runtime.h>

#define HH 384
#define HWPX (HH*HH)

// ws float-offset layout
#define WOFF3 16
#define HS3   40      // D=3,  DP=4 : 2*3*4  + 3*4  + 4
#define WOFF6 256     // 16 + 6*40
#define HS6   328     // D=12, DP=12: 2*12*12+ 3*12 + 4
#define WOFF9 1568    // 256 + 4*328
#define HS9   1600    // D=27, DP=28: 2*27*28+ 3*28 + 4
#define CATOFF 8192
#define P9BOFF (CATOFF + 2*9*HWPX)
#define WS_NEED ((size_t)(P9BOFF + 2*3*HWPX) * 4)

__device__ __forceinline__ float4 fma4s(float4 a, float4 w, float t) {
    a.x += w.x * t; a.y += w.y * t; a.z += w.z * t; a.w += w.w * t; return a;
}
__device__ __forceinline__ float dot4(float4 a, float4 b) {
    return a.x * b.x + a.y * b.y + a.z * b.z + a.w * b.w;
}

// ---------------- precompute weights + xg max ----------------
__global__ __launch_bounds__(256) void pre_xg(
    const float* __restrict__ w3q, const float* __restrict__ b3q,
    const float* __restrict__ w3k, const float* __restrict__ b3k,
    const float* __restrict__ w3v, const float* __restrict__ b3v, const float* __restrict__ hw3,
    const float* __restrict__ w6q, const float* __restrict__ b6q,
    const float* __restrict__ w6k, const float* __restrict__ b6k,
    const float* __restrict__ w6v, const float* __restrict__ b6v, const float* __restrict__ hw6,
    const float* __restrict__ w9q, const float* __restrict__ b9q,
    const float* __restrict__ w9k, const float* __restrict__ b9k,
    const float* __restrict__ w9v, const float* __restrict__ b9v, const float* __restrict__ hw9,
    const float* __restrict__ x, float* __restrict__ ws)
{
    __shared__ float sm[4];
    const int blk = blockIdx.x;
    const int tid = threadIdx.x;

    if (blk < 12) {
        int stage = blk < 6 ? 0 : (blk < 10 ? 1 : 2);
        int h = blk - (stage == 0 ? 0 : (stage == 1 ? 6 : 10));
        const float* WQ[3] = {w3q, w6q, w9q};
        const float* BQ[3] = {b3q, b6q, b9q};
        const float* WK[3] = {w3k, w6k, w9k};
        const float* BK[3] = {b3k, b6k, b9k};
        const float* WV_[3] = {w3v, w6v, w9v};
        const float* BV[3] = {b3v, b6v, b9v};
        const float* HWp[3] = {hw3, hw6, hw9};
        const int Ds[3] = {3, 12, 27};
        const int DPs[3] = {4, 12, 28};
        const int WOFFs[3] = {WOFF3, WOFF6, WOFF9};
        const int HSs[3] = {HS3, HS6, HS9};

        const int D = Ds[stage], DP = DPs[stage];
        const float* wq = WQ[stage] + h * D * D;
        const float* bq = BQ[stage] + h * D;
        const float* wk = WK[stage] + h * D * D;
        const float* bk = BK[stage] + h * D;
        const float* wv = WV_[stage] + h * D * D;
        const float* bv = BV[stage] + h * D;
        const float hwv = HWp[stage][h];
        float* base = ws + WOFFs[stage] + h * HSs[stage];
        const float scale = rsqrtf((float)D);

        for (int i = tid; i < D * DP; i += 256) {
            int a = i / DP, b = i % DP;
            float m = 0.f;
            if (b < D) for (int e = 0; e < D; ++e) m += wk[e * D + b] * wq[e * D + a];
            base[i] = scale * m;                       // M[a][d]
            float wvv = 0.f;
            if (b < D) wvv = hwv * wv[a * D + b];
            base[D * DP + i] = wvv;                    // WV[e][d]
        }
        for (int i = tid; i < DP; i += 256) {
            float cv = 0.f, uv = 0.f;
            if (i < D) for (int e = 0; e < D; ++e) {
                cv += bq[e] * wk[e * D + i];
                uv += wq[e * D + i] * bk[e];
            }
            base[2 * D * DP + i] = scale * cv;         // c
            base[2 * D * DP + DP + i] = scale * uv;    // u
            base[2 * D * DP + 2 * DP + i] = (i < D) ? hwv * bv[i] : 0.f;   // bvh
        }
        if (tid == 0) {
            float s = 0.f;
            for (int e = 0; e < D; ++e) s += bq[e] * bk[e];
            base[2 * D * DP + 3 * DP] = scale * s;     // s0
        }
    } else {
        int i2 = blk - 12;
        int b = i2 / 144, chunk = i2 % 144;
        const float4* xb = (const float4*)(x + (size_t)b * 3 * HWPX + chunk * 3072);
        float m = 0.f;
        for (int j = tid; j < 768; j += 256) {
            float4 v = xb[j];
            m = fmaxf(m, fmaxf(fmaxf(v.x, v.y), fmaxf(v.z, v.w)));
        }
        for (int off = 32; off; off >>= 1)
            m = fmaxf(m, __shfl_down(m, off));
        if ((tid & 63) == 0) sm[tid >> 6] = m;
        __syncthreads();
        if (tid == 0) {
            float mm = fmaxf(fmaxf(sm[0], sm[1]), fmaxf(sm[2], sm[3]));
            atomicMax((int*)&ws[b], __float_as_int(mm));  // poison is negative int; mm>=0 wins
        }
    }
}

// ---------------- attention stage: cell-major LDS + LDS weights + fused softmax ----------------
// Block: 16x16 windows, 256 threads (1 window/thread). Heads split across blockIdx.z (HSPLIT).
template <int P, int HEADS, int HSPLIT>
__global__ __launch_bounds__(256) void attn_cell(
    const float* __restrict__ in, long in_bstride,
    float* __restrict__ outA, long outA_bstride,
    float* __restrict__ outB, long outB_bstride,
    const float* __restrict__ wsw)
{
    constexpr int C = 3, D = C * P * P, DP = (D + 3) & ~3, NREG = DP / 4;
    constexpr int HS = 2 * D * DP + 3 * DP + 4;
    constexpr int HPT = HEADS / HSPLIT;
    __shared__ __align__(16) float scell[324 * DP];     // 18x18 cells
    __shared__ __align__(16) float sw[HPT * HS];

    const int tid = threadIdx.x;
    const int z = blockIdx.z;
    const int b = z & 1;
    const int hs = z >> 1;
    const int BWY = blockIdx.y * 16, BWX = blockIdx.x * 16;

    const float* inb = in + (size_t)b * in_bstride;
    constexpr int XW = 18 * P;
    constexpr int TOT = 3 * P * 18 * XW;
    for (int i = tid; i < TOT; i += 256) {
        int c = i / (P * 18 * XW);
        int rem = i % (P * 18 * XW);
        int r = rem / (18 * XW);
        int rem2 = rem % (18 * XW);
        int cy = rem2 / XW, xx = rem2 % XW;
        int y = (BWY + cy) * P + r - P; y = y < 0 ? -y : (y >= HH ? 2 * HH - 2 - y : y);
        int x = BWX * P + xx - P;       x = x < 0 ? -x : (x >= HH ? 2 * HH - 2 - x : x);
        int cx = xx / P, s = xx % P;
        scell[(cy * 18 + cx) * DP + (c * P + r) * P + s] = inb[c * HWPX + y * HH + x];
    }
    if constexpr (DP > D) {   // zero the pad lane so 0*junk can't make NaN
        for (int j = tid; j < 324; j += 256) scell[j * DP + D] = 0.f;
    }
    const float* wsrc = wsw + (size_t)hs * HPT * HS;
    for (int i = tid; i < HPT * HS; i += 256) sw[i] = wsrc[i];
    __syncthreads();

    const int wx = tid & 15, wy = tid >> 4;

    float t4[DP];
    {
        const float4* T4p = (const float4*)&scell[((wy + 1) * 18 + wx + 1) * DP];
#pragma unroll
        for (int k = 0; k < NREG; ++k) {
            float4 v = T4p[k];
            t4[4 * k] = v.x; t4[4 * k + 1] = v.y; t4[4 * k + 2] = v.z; t4[4 * k + 3] = v.w;
        }
    }
    float mixed[D];
#pragma unroll
    for (int e = 0; e < D; ++e) mixed[e] = 0.f;

#pragma unroll 1
    for (int hh = 0; hh < HPT; ++hh) {
        const float* hb = sw + hh * HS;
        const float* ccb = hb + 2 * D * DP;
        float4 qk[NREG];
        {
            const float4* cp = (const float4*)ccb;
#pragma unroll
            for (int k = 0; k < NREG; ++k) qk[k] = cp[k];
        }
        float su = ccb[3 * DP];
#pragma unroll
        for (int a = 0; a < D; ++a) {
            const float t = t4[a];
            su += ccb[DP + a] * t;
            const float4* Mr = (const float4*)(hb + a * DP);
#pragma unroll
            for (int k = 0; k < NREG; ++k) qk[k] = fma4s(qk[k], Mr[k], t);
        }
        // fused scores + exp + weighting (scores ~O(0.01): exp w/o max-sub is safe)
        float denom = 0.f;
        float4 wt[NREG];
#pragma unroll
        for (int k = 0; k < NREG; ++k) wt[k] = make_float4(0.f, 0.f, 0.f, 0.f);
#pragma unroll
        for (int di = 0; di < 3; ++di)
#pragma unroll
            for (int dj = 0; dj < 3; ++dj) {
                const float4* cp = (const float4*)&scell[((wy + di) * 18 + wx + dj) * DP];
                float4 cv[NREG];
#pragma unroll
                for (int k = 0; k < NREG; ++k) cv[k] = cp[k];
                float s = su;
#pragma unroll
                for (int k = 0; k < NREG; ++k) s += dot4(qk[k], cv[k]);
                const float e = __expf(s);
                denom += e;
#pragma unroll
                for (int k = 0; k < NREG; ++k) wt[k] = fma4s(wt[k], cv[k], e);
            }
        const float winv = 1.f / denom;
#pragma unroll
        for (int k = 0; k < NREG; ++k) {
            wt[k].x *= winv; wt[k].y *= winv; wt[k].z *= winv; wt[k].w *= winv;
        }
        const float* WVb = hb + D * DP;
#pragma unroll
        for (int e = 0; e < D; ++e) {
            const float4* Wr = (const float4*)(WVb + e * DP);
            float o = ccb[2 * DP + e];
#pragma unroll
            for (int k = 0; k < NREG; ++k) o += dot4(Wr[k], wt[k]);
            mixed[e] += o;
        }
    }

    float* outp = (hs == 0) ? (outA + (size_t)b * outA_bstride)
                            : (outB + (size_t)b * outB_bstride);
#pragma unroll
    for (int c = 0; c < C; ++c)
#pragma unroll
        for (int r = 0; r < P; ++r)
#pragma unroll
            for (int s = 0; s < P; ++s)
                outp[c * HWPX + ((BWY + wy) * P + r) * HH + (BWX + wx) * P + s] =
                    mixed[(c * P + r) * P + s];
}

// ---------------- conv0 (5x5, zero-pad 2) + final elementwise ----------------
__global__ __launch_bounds__(128) void conv_final(
    const float* __restrict__ cat, const float* __restrict__ p9b, int addp9,
    const float* __restrict__ w, const float* __restrict__ bias,
    const float* __restrict__ x, const float* __restrict__ xg,
    float* __restrict__ out)
{
    __shared__ float tile[9][20][40];
    const int tid = threadIdx.x;
    const int b = blockIdx.z;
    const int bx = blockIdx.x * 32, by = blockIdx.y * 16;
    const float* catb = cat + (size_t)b * 9 * HWPX;
    const float* p9bb = p9b + (size_t)b * 3 * HWPX;

    for (int i = tid; i < 9 * 20 * 10; i += 128) {
        int ci = i / 200;
        int rem = i % 200;
        int row = rem / 10, c4 = rem % 10;
        int y = by + row - 2, xx = bx - 4 + 4 * c4;
        float4 v = {0.f, 0.f, 0.f, 0.f};
        if (y >= 0 && y < HH && xx >= 0 && xx <= HH - 4) {
            v = *(const float4*)&catb[ci * HWPX + y * HH + xx];
            if (addp9 && ci < 3) {
                float4 u = *(const float4*)&p9bb[ci * HWPX + y * HH + xx];
                v.x += u.x; v.y += u.y; v.z += u.z; v.w += u.w;
            }
        }
        *(float4*)&tile[ci][row][4 * c4] = v;
    }
    __syncthreads();

    const int tx = tid & 7, ty = tid >> 3;
    float acc0[4], acc1[4], acc2[4];
    const float b0 = bias[0], b1 = bias[1], b2 = bias[2];
#pragma unroll
    for (int j = 0; j < 4; ++j) { acc0[j] = b0; acc1[j] = b1; acc2[j] = b2; }

#pragma unroll
    for (int ky = 0; ky < 5; ++ky) {
#pragma unroll 1
        for (int ci = 0; ci < 9; ++ci) {
            const float4 ra = *(const float4*)&tile[ci][ty + ky][4 * tx];
            const float4 rb = *(const float4*)&tile[ci][ty + ky][4 * tx + 4];
            const float4 rc = *(const float4*)&tile[ci][ty + ky][4 * tx + 8];
            const float r[12] = {ra.x, ra.y, ra.z, ra.w, rb.x, rb.y, rb.z, rb.w,
                                 rc.x, rc.y, rc.z, rc.w};
            const float* __restrict__ w0 = w + (0 * 9 + ci) * 25 + ky * 5;
            const float* __restrict__ w1 = w + (1 * 9 + ci) * 25 + ky * 5;
            const float* __restrict__ w2 = w + (2 * 9 + ci) * 25 + ky * 5;
#pragma unroll
            for (int j = 0; j < 4; ++j)
#pragma unroll
                for (int kx = 0; kx < 5; ++kx) {
                    const float t = r[j + kx + 2];
                    acc0[j] += t * w0[kx];
                    acc1[j] += t * w1[kx];
                    acc2[j] += t * w2[kx];
                }
        }
    }

    const int yb = by + ty, xb = bx + 4 * tx;
    const float xgv = xg[b];
    float* accs[3] = {acc0, acc1, acc2};
#pragma unroll
    for (int co = 0; co < 3; ++co) {
        const float4 xv = *(const float4*)&x[((size_t)(b * 3 + co)) * HWPX + yb * HH + xb];
        const float* a = accs[co];
        float4 ov;
        float x0;
        x0 = fmaxf(a[0], 0.f); ov.x = fmaxf(xv.x * x0 + xgv - x0, 0.f);
        x0 = fmaxf(a[1], 0.f); ov.y = fmaxf(xv.y * x0 + xgv - x0, 0.f);
        x0 = fmaxf(a[2], 0.f); ov.z = fmaxf(xv.z * x0 + xgv - x0, 0.f);
        x0 = fmaxf(a[3], 0.f); ov.w = fmaxf(xv.w * x0 + xgv - x0, 0.f);
        *(float4*)&out[((size_t)(b * 3 + co)) * HWPX + yb * HH + xb] = ov;
    }
}

// ---------------- launch ----------------
extern "C" void kernel_launch(void* const* d_in, const int* in_sizes, int n_in,
                              void* d_out, int out_size, void* d_ws, size_t ws_size,
                              hipStream_t stream) {
    const float* x   = (const float*)d_in[0];
    const float* w3q = (const float*)d_in[1];
    const float* b3q = (const float*)d_in[2];
    const float* w3k = (const float*)d_in[3];
    const float* b3k = (const float*)d_in[4];
    const float* w3v = (const float*)d_in[5];
    const float* b3v = (const float*)d_in[6];
    const float* hw3 = (const float*)d_in[7];
    const float* w6q = (const float*)d_in[8];
    const float* b6q = (const float*)d_in[9];
    const float* w6k = (const float*)d_in[10];
    const float* b6k = (const float*)d_in[11];
    const float* w6v = (const float*)d_in[12];
    const float* b6v = (const float*)d_in[13];
    const float* hw6 = (const float*)d_in[14];
    const float* w9q = (const float*)d_in[15];
    const float* b9q = (const float*)d_in[16];
    const float* w9k = (const float*)d_in[17];
    const float* b9k = (const float*)d_in[18];
    const float* w9v = (const float*)d_in[19];
    const float* b9v = (const float*)d_in[20];
    const float* hw9 = (const float*)d_in[21];
    const float* c0w = (const float*)d_in[22];
    const float* c0b = (const float*)d_in[23];

    float* out = (float*)d_out;
    float* ws  = (float*)d_ws;
    float* cat = ws + CATOFF;
    float* p9b = ws + P9BOFF;
    const bool split9 = ws_size >= WS_NEED;

    pre_xg<<<300, 256, 0, stream>>>(
        w3q, b3q, w3k, b3k, w3v, b3v, hw3,
        w6q, b6q, w6k, b6k, w6v, b6v, hw6,
        w9q, b9q, w9k, b9k, w9v, b9v, hw9, x, ws);

    // stage3: p=1, 6 heads -> cat ch6..8
    attn_cell<1, 6, 1><<<dim3(24, 24, 2), 256, 0, stream>>>(
        x, 3 * HWPX, cat + 6 * HWPX, 9 * HWPX, cat + 6 * HWPX, 9 * HWPX, ws + WOFF3);
    // stage6: p=2, 4 heads -> cat ch3..5
    attn_cell<2, 4, 1><<<dim3(12, 12, 2), 256, 0, stream>>>(
        cat + 6 * HWPX, 9 * HWPX, cat + 3 * HWPX, 9 * HWPX, cat + 3 * HWPX, 9 * HWPX, ws + WOFF6);
    // stage9: p=3, 2 heads, head h=0 -> cat ch0..2, h=1 -> p9b (summed in conv)
    if (split9)
        attn_cell<3, 2, 2><<<dim3(8, 8, 4), 256, 0, stream>>>(
            cat + 3 * HWPX, 9 * HWPX, cat, 9 * HWPX, p9b, 3 * HWPX, ws + WOFF9);
    else
        attn_cell<3, 2, 1><<<dim3(8, 8, 2), 256, 0, stream>>>(
            cat + 3 * HWPX, 9 * HWPX, cat, 9 * HWPX, cat, 9 * HWPX, ws + WOFF9);

    conv_final<<<dim3(12, 24, 2), 128, 0, stream>>>(
        cat, p9b, split9 ? 1 : 0, c0w, c0b, x, ws, out);
}